// Round 7
// baseline (695.045 us; speedup 1.0000x reference)
//
#include <hip/hip_runtime.h>
#include <stdint.h>

#define T_TOK 1024
#define HID   2048
#define NE    8
#define INTER 5632
#define I2    11264
#define MAXT  24     // worst-case sum ceil(c64/128) over experts
#define RMAX  2560
#define KCH   1408   // INTER/4, GEMM2 K-split chunk

typedef __bf16 bf16x8 __attribute__((ext_vector_type(8)));
typedef float  f32x4  __attribute__((ext_vector_type(4)));
typedef unsigned short u16;

typedef __attribute__((address_space(3))) uint32_t lds_u32;
typedef __attribute__((address_space(1))) uint32_t glb_u32;

// async global->LDS, 16B per lane; LDS dest must be the WAVE-UNIFORM base
// (HW adds lane*16); global src is per-lane.
__device__ __forceinline__ void gload16(const void* g, void* l) {
    __builtin_amdgcn_global_load_lds((const glb_u32*)g, (lds_u32*)l, 16, 0, 0);
}

// read 8 f32 from a swizzled LDS row, convert to bf16x8 fragment
__device__ __forceinline__ bf16x8 f32frag(const char* rowbase, int sw, int cb) {
    float4 f0 = *(const float4*)(rowbase + ((cb) ^ sw));
    float4 f1 = *(const float4*)(rowbase + ((cb + 16) ^ sw));
    bf16x8 r;
    r[0] = (__bf16)f0.x; r[1] = (__bf16)f0.y; r[2] = (__bf16)f0.z; r[3] = (__bf16)f0.w;
    r[4] = (__bf16)f1.x; r[5] = (__bf16)f1.y; r[6] = (__bf16)f1.z; r[7] = (__bf16)f1.w;
    return r;
}

#define MFMA __builtin_amdgcn_mfma_f32_16x16x32_bf16
#define SBAR __builtin_amdgcn_s_barrier
#define SCHB __builtin_amdgcn_sched_barrier

// 8 async loads per wave into buffer B; sources pre-offset per lane.
#define STAGE(B, KT)                                                         \
    _Pragma("unroll")                                                        \
    for (int i = 0; i < 8; ++i)                                              \
        gload16(srcp[i] + (KT) * kstepB, smem + dbase + (B) * dstride + i * 1024);

__global__ void moe_router(const float* __restrict__ logits,
                           int* __restrict__ mi, float* __restrict__ mf) {
    int t = blockIdx.x * blockDim.x + threadIdx.x;
    if (t >= T_TOK) return;
    float l[NE];
#pragma unroll
    for (int i = 0; i < NE; ++i) l[i] = logits[t * NE + i];
    int e0 = 0; float v0 = l[0];
#pragma unroll
    for (int i = 1; i < NE; ++i) if (l[i] > v0) { v0 = l[i]; e0 = i; }
    int e1 = -1; float v1 = -3.4e38f;
#pragma unroll
    for (int i = 0; i < NE; ++i) if (i != e0 && l[i] > v1) { v1 = l[i]; e1 = i; }
    float ex = __expf(v1 - v0);
    float s  = 1.f + ex;
    mi[256 + 2 * t]     = e0;
    mi[256 + 2 * t + 1] = e1;
    mf[8192 + 2 * t]     = 1.f / s;
    mf[8192 + 2 * t + 1] = ex / s;
    atomicAdd(&mi[e0], 1);
    atomicAdd(&mi[e1], 1);
}

__global__ void moe_plan(int* __restrict__ mi) {
    int tid = threadIdx.x;
    if (tid == 0) {
        int off = 0, nt = 0;
        for (int e = 0; e < NE; ++e) {
            int c = mi[e];
            mi[24 + e] = off;
            int c64 = ((c + 63) >> 6) << 6;
            int ntile = (c64 + 127) >> 7;
            for (int j = 0; j < ntile; ++j) {
                mi[32 + 2 * nt]     = e;
                mi[32 + 2 * nt + 1] = off + j * 128;
                ++nt;
            }
            off += c64;
            mi[8 + e] = 0;
        }
        mi[16] = nt;
    }
    for (int i = tid; i < RMAX; i += blockDim.x) mi[2560 + i] = -1;
}

__global__ void moe_scatter(int* __restrict__ mi, float* __restrict__ mf) {
    int t = blockIdx.x * blockDim.x + threadIdx.x;
    if (t >= T_TOK) return;
    int e0 = mi[256 + 2 * t], e1 = mi[256 + 2 * t + 1];
    float w0 = mf[8192 + 2 * t], w1 = mf[8192 + 2 * t + 1];
    int p0 = atomicAdd(&mi[8 + e0], 1);
    int s0 = mi[24 + e0] + p0;
    mi[2560 + s0] = t; mf[5632 + s0] = w0;
    int p1 = atomicAdd(&mi[8 + e1], 1);
    int s1 = mi[24 + e1] + p1;
    mi[2560 + s1] = t; mf[5632 + s1] = w1;
}

// ---- GEMM1: 128x(64g+64u), BK=32, gload_lds dbuf + counted vmcnt ----------
// LDS: A bufs [0,32768) (2x16KB), Bg [32768,49152) (2x8KB),
//      Bu [49152,65536) (2x8KB), toks @65536.

#define COMP1(CUR)                                                           \
  { const char* Ab  = smem + (CUR) * 16384;                                  \
    const char* Bgb = smem + 32768 + (CUR) * 8192;                           \
    const char* Bub = smem + 49152 + (CUR) * 8192;                           \
    bf16x8 a0 = f32frag(Ab + (w * 32 + lrow) * 128, sw, lk * 32);            \
    bf16x8 a1 = f32frag(Ab + (w * 32 + 16 + lrow) * 128, sw, lk * 32);       \
    _Pragma("unroll")                                                        \
    for (int fn = 0; fn < 4; ++fn) {                                         \
        bf16x8 bg = f32frag(Bgb + (fn * 16 + lrow) * 128, sw, lk * 32);      \
        bf16x8 bu = f32frag(Bub + (fn * 16 + lrow) * 128, sw, lk * 32);      \
        accg[0][fn] = MFMA(a0, bg, accg[0][fn], 0, 0, 0);                    \
        accg[1][fn] = MFMA(a1, bg, accg[1][fn], 0, 0, 0);                    \
        accu[0][fn] = MFMA(a0, bu, accu[0][fn], 0, 0, 0);                    \
        accu[1][fn] = MFMA(a1, bu, accu[1][fn], 0, 0, 0);                    \
    } }

__global__ __launch_bounds__(256) void moe_gemm1(
        const float* __restrict__ hidden, const float* __restrict__ w13,
        const int* __restrict__ mi, u16* __restrict__ act) {
    const int ct = blockIdx.x, tj = blockIdx.y;   // ct-major: tj pairs land on same XCD
    if (tj >= mi[16]) return;
    const int e = mi[32 + 2 * tj], row_base = mi[32 + 2 * tj + 1];
    const int* rowtok = mi + 2560;
    const int limit = mi[24 + e] + (((mi[e] + 63) >> 6) << 6);

    __shared__ __align__(16) char smem[66048];
    int* toks = (int*)(smem + 65536);

    const int tid = threadIdx.x;
    const int w = tid >> 6, lane = tid & 63;
    const int lrow = lane & 15, lk = lane >> 4;
    const int li = lane >> 3, lc = lane & 7;     // staging: row-in-8, 16B chunk
    const int sw = (lrow & 7) << 4;

    if (tid < 128) {
        int idx = row_base + tid;
        toks[tid] = (idx < limit) ? rowtok[idx] : -1;
    }
    __syncthreads();

    // per-wave staging role: w0/w1 -> A rows, w2 -> gate, w3 -> up.
    // source chunk pre-swizzled: LDS chunk c holds global chunk c^(row&7).
    const char* srcp[8];
    const int kstepB = 128;                       // 32 f32 per K-step
    int dbase, dstride;
    if (w < 2) {
        dbase = w * 8192; dstride = 16384;
#pragma unroll
        for (int i = 0; i < 8; ++i) {
            int tok = toks[w * 64 + i * 8 + li];
            if (tok < 0) tok = 0;                 // garbage rows masked at store
            srcp[i] = (const char*)(hidden + (size_t)tok * HID) + ((lc ^ li) << 4);
        }
    } else {
        dbase = (w == 2) ? 32768 : 49152; dstride = 8192;
        const float* wb = w13 + ((size_t)e * I2 + (w == 3 ? INTER : 0)
                                 + (size_t)ct * 64) * HID;
#pragma unroll
        for (int i = 0; i < 8; ++i)
            srcp[i] = (const char*)(wb + (size_t)(i * 8 + li) * HID) + ((lc ^ li) << 4);
    }

    f32x4 accg[2][4] = {}, accu[2][4] = {};

    STAGE(0, 0);
    int cur = 0;
    for (int kt = 0; kt < 63; ++kt) {
        STAGE(cur ^ 1, kt + 1);
        asm volatile("s_waitcnt vmcnt(8)" ::: "memory");
        SCHB(0);
        SBAR();
        SCHB(0);
        COMP1(cur);
        SCHB(0);
        SBAR();
        cur ^= 1;
    }
    asm volatile("s_waitcnt vmcnt(0)" ::: "memory");
    SCHB(0);
    SBAR();
    SCHB(0);
    COMP1(cur);

    // epilogue: silu(g)*u -> act, stored column-swizzled (gemm2 un-swizzles)
    const size_t actbase = (size_t)row_base * INTER + (size_t)ct * 64;
#pragma unroll
    for (int fm = 0; fm < 2; ++fm)
#pragma unroll
    for (int fn = 0; fn < 4; ++fn)
#pragma unroll
    for (int j = 0; j < 4; ++j) {
        int row = w * 32 + fm * 16 + lk * 4 + j;
        int col = fn * 16 + lrow;
        if (toks[row] >= 0) {
            float g = accg[fm][fn][j], u = accu[fm][fn][j];
            float a = g / (1.f + __expf(-g)) * u;
            int colw = col ^ ((row & 7) << 3);
            ((__bf16*)act)[actbase + (size_t)row * INTER + colw] = (__bf16)a;
        }
    }
}

// ---- GEMM2: 128x64 per (ct,tj,kz), BK=64, same pipeline ------------------
// LDS: A bufs [0,32768) (2x16KB bf16, pre-swizzled content, linear gload),
//      B bufs [32768,65536) (2x16KB f32, 256B rows).

#define COMP2(CUR)                                                           \
  { const char* Ab = smem + (CUR) * 16384;                                   \
    const char* Bb = smem + 32768 + (CUR) * 16384;                           \
    _Pragma("unroll")                                                        \
    for (int kk = 0; kk < 2; ++kk) {                                         \
        bf16x8 a0 = *(const bf16x8*)(Ab + (w * 32 + lrow) * 128              \
                                     + ((kk * 64 + lk * 16) ^ sw));          \
        bf16x8 a1 = *(const bf16x8*)(Ab + (w * 32 + 16 + lrow) * 128         \
                                     + ((kk * 64 + lk * 16) ^ sw));          \
        _Pragma("unroll")                                                    \
        for (int fn = 0; fn < 4; ++fn) {                                     \
            bf16x8 b = f32frag(Bb + (fn * 16 + lrow) * 256, sw,              \
                               kk * 128 + lk * 32);                          \
            acc[0][fn] = MFMA(a0, b, acc[0][fn], 0, 0, 0);                   \
            acc[1][fn] = MFMA(a1, b, acc[1][fn], 0, 0, 0);                   \
        }                                                                    \
    } }

__global__ __launch_bounds__(256) void moe_gemm2(
        const u16* __restrict__ act, const float* __restrict__ w2,
        const int* __restrict__ mi, const float* __restrict__ mf,
        float* __restrict__ out) {
    const int ct = blockIdx.x, tj = blockIdx.y, kz = blockIdx.z;
    if (tj >= mi[16]) return;
    const int e = mi[32 + 2 * tj], row_base = mi[32 + 2 * tj + 1];
    const int* rowtok = mi + 2560;
    const float* roww = mf + 5632;
    const int limit = mi[24 + e] + (((mi[e] + 63) >> 6) << 6);

    __shared__ __align__(16) char smem[65536];

    const int tid = threadIdx.x;
    const int w = tid >> 6, lane = tid & 63;
    const int lrow = lane & 15, lk = lane >> 4;
    const int li = lane >> 3, lc = lane & 7;      // 128B-row staging
    const int li2 = lane >> 4, lc2 = lane & 15;   // 256B-row staging
    const int sw = (lrow & 7) << 4;
    const int kbeg = kz * KCH;

    const char* srcp[8];
    int dbase, kstepB;
    const int dstride = 16384;
    if (w < 2) {
        kstepB = 128;                             // 64 bf16 per K-step
        dbase = w * 8192;
#pragma unroll
        for (int i = 0; i < 8; ++i) {
            int slot = row_base + w * 64 + i * 8 + li;
            if (slot > RMAX - 1) slot = RMAX - 1; // garbage rows masked at store
            srcp[i] = (const char*)(act + (size_t)slot * INTER + kbeg) + (lc << 4);
        }
    } else {
        kstepB = 256;                             // 64 f32 per K-step
        dbase = 32768 + (w - 2) * 8192;
        const float* wb = w2 + ((size_t)e * HID + (size_t)ct * 64) * INTER + kbeg;
#pragma unroll
        for (int i = 0; i < 8; ++i) {
            int r = (w - 2) * 32 + i * 4 + li2;
            srcp[i] = (const char*)(wb + (size_t)r * INTER) + ((lc2 ^ (r & 7)) << 4);
        }
    }

    f32x4 acc[2][4] = {};

    STAGE(0, 0);
    int cur = 0;
    for (int kt = 0; kt < 21; ++kt) {
        STAGE(cur ^ 1, kt + 1);
        asm volatile("s_waitcnt vmcnt(8)" ::: "memory");
        SCHB(0);
        SBAR();
        SCHB(0);
        COMP2(cur);
        SCHB(0);
        SBAR();
        cur ^= 1;
    }
    asm volatile("s_waitcnt vmcnt(0)" ::: "memory");
    SCHB(0);
    SBAR();
    SCHB(0);
    COMP2(cur);

#pragma unroll
    for (int fm = 0; fm < 2; ++fm)
#pragma unroll
    for (int fn = 0; fn < 4; ++fn)
#pragma unroll
    for (int j = 0; j < 4; ++j) {
        int row = w * 32 + fm * 16 + lk * 4 + j;
        int col = fn * 16 + lrow;
        int slot = row_base + row;
        if (slot < limit) {
            int tok = rowtok[slot];
            if (tok >= 0)
                atomicAdd(out + (size_t)tok * HID + (size_t)ct * 64 + col,
                          acc[fm][fn][j] * roww[slot]);
        }
    }
}

extern "C" void kernel_launch(void* const* d_in, const int* in_sizes, int n_in,
                              void* d_out, int out_size, void* d_ws, size_t ws_size,
                              hipStream_t stream) {
    const float* hidden = (const float*)d_in[0];
    const float* logits = (const float*)d_in[1];
    const float* w13    = (const float*)d_in[2];
    const float* w2     = (const float*)d_in[3];
    float* out = (float*)d_out;

    int*   mi  = (int*)d_ws;
    float* mf  = (float*)d_ws;
    u16*   act = (u16*)((char*)d_ws + 65536);

    hipMemsetAsync(d_ws, 0, 64, stream);
    hipMemsetAsync(d_out, 0, (size_t)out_size * sizeof(float), stream);

    moe_router<<<dim3(T_TOK / 256), 256, 0, stream>>>(logits, mi, mf);
    moe_plan<<<dim3(1), 256, 0, stream>>>(mi);
    moe_scatter<<<dim3(T_TOK / 256), 256, 0, stream>>>(mi, mf);
    moe_gemm1<<<dim3(INTER / 64, MAXT), 256, 0, stream>>>(hidden, w13, mi, act);
    moe_gemm2<<<dim3(HID / 64, MAXT, INTER / KCH), 256, 0, stream>>>(act, w2, mi, mf, out);
}